// Round 15
// baseline (262.966 us; speedup 1.0000x reference)
//
#include <hip/hip_runtime.h>
#include <hip/hip_bf16.h>

#define D 128
#define EPS 1e-5f
#define CHK 8192            // edges per phase-1 chunk
#define P2CAP 6144          // max edges per 256-dst bucket

typedef __attribute__((ext_vector_type(8))) short short8;
typedef __attribute__((ext_vector_type(4))) float float4v;

#define AS1 __attribute__((address_space(1)))
#define AS3 __attribute__((address_space(3)))

__device__ inline ushort f2bf(float f) {
    __hip_bfloat16 b = __float2bfloat16(f);
    return *reinterpret_cast<ushort*>(&b);
}
__device__ inline float bf_lo(uint u) { return __uint_as_float(u << 16); }
__device__ inline float bf_hi(uint u) { return __uint_as_float(u & 0xffff0000u); }

// ---------- K1: weight-convert (blocks 0..12) + chunk-hist (fused k_c1,
// blocks 13..13+C-1) + LN1+ReLU (all blocks >= 13) -------------------------
__global__ void k_ln1cvt(const float* __restrict__ x, const int* __restrict__ ntp,
                         const float* __restrict__ gamma, const float* __restrict__ beta,
                         ushort* __restrict__ y,
                         const float* __restrict__ Wrel, const float* __restrict__ Wroot,
                         const float* __restrict__ Wmlp, ushort* __restrict__ Wt,
                         const int* __restrict__ edst, int* __restrict__ hist,
                         int N, int E, int C, int B) {
    __shared__ ushort t[128][136];
    __shared__ int cnt[256];
    if (blockIdx.x < 13) {
        int m = blockIdx.x;
        const float* src = (m == 0) ? Wroot
                         : (m <= 8) ? Wrel + (size_t)(m - 1) * D * D
                                    : Wmlp + (size_t)(m - 9) * D * D;
        for (int i = threadIdx.x; i < D * D; i += 256) {
            int k = i >> 7, n = i & 127;
            t[n][k] = f2bf(src[i]);
        }
        __syncthreads();
        ushort* dst = Wt + (size_t)m * D * D;
        for (int i = threadIdx.x; i < D * D; i += 256) {
            int frag = i >> 9;
            int lane = (i >> 3) & 63;
            int j = i & 7;
            int nt = frag >> 2, ks = frag & 3;
            int n = nt * 16 + (lane & 15);
            int k = ks * 32 + (lane >> 4) * 8 + j;
            dst[i] = t[n][k];
        }
        return;
    }
    int c = blockIdx.x - 13;
    if (c < C) {
        int tid = threadIdx.x;
        cnt[tid] = 0;
        __syncthreads();
        #pragma unroll 4
        for (int k = 0; k < CHK / 256; ++k) {
            int e = c * CHK + k * 256 + tid;
            if (e < E) atomicAdd(&cnt[edst[e] >> 8], 1);
        }
        __syncthreads();
        if (tid < B) hist[c * B + tid] = cnt[tid];
    }
    int n = (blockIdx.x - 13) * 4 + (threadIdx.x >> 6);
    if (n >= N) return;
    int l = threadIdx.x & 63;
    float2 v = *(const float2*)(x + (size_t)n * D + 2 * l);
    float s = v.x + v.y, s2 = v.x * v.x + v.y * v.y;
    #pragma unroll
    for (int o = 32; o; o >>= 1) { s += __shfl_xor(s, o, 64); s2 += __shfl_xor(s2, o, 64); }
    float mu = s * (1.0f / D);
    float var = s2 * (1.0f / D) - mu * mu;
    float inv = rsqrtf(var + EPS);
    int tt = ntp[n];
    float2 g = *(const float2*)(gamma + tt * D + 2 * l);
    float2 b = *(const float2*)(beta + tt * D + 2 * l);
    float a0 = fmaxf((v.x - mu) * inv * g.x + b.x, 0.0f);
    float a1 = fmaxf((v.y - mu) * inv * g.y + b.y, 0.0f);
    ((uint*)(y + (size_t)n * D))[l] = ((uint)f2bf(a1) << 16) | f2bf(a0);
}

// ---------- two-phase edge sort by dst (R14 forms, proven) --------------------
__global__ void k_c2(const int* __restrict__ hist, int* __restrict__ chunkoff,
                     int* __restrict__ bucktot, int C, int B) {
    __shared__ int v[128];
    int b = blockIdx.x, t = threadIdx.x;
    v[t] = (t < C) ? hist[t * B + b] : 0;
    __syncthreads();
    if (t == 0) {
        int s = 0;
        for (int c = 0; c < C; ++c) { int x = v[c]; v[c] = s; s += x; }
        bucktot[b] = s;
    }
    __syncthreads();
    if (t < C) chunkoff[t * B + b] = v[t];
}
__global__ void k_p1s(const int* __restrict__ edst, const int* __restrict__ esrc,
                      const int* __restrict__ etyp, const int* __restrict__ bucktot,
                      const int* __restrict__ chunkoff, uint* __restrict__ edata,
                      int E, int B) {
    __shared__ int ps[256];
    __shared__ int base[256];
    __shared__ int cnt[256];
    int c = blockIdx.x, tid = threadIdx.x;
    int bt = (tid < B) ? bucktot[tid] : 0;
    ps[tid] = bt;
    __syncthreads();
    for (int o = 1; o < 256; o <<= 1) {
        int v = (tid >= o) ? ps[tid - o] : 0;
        __syncthreads();
        ps[tid] += v;
        __syncthreads();
    }
    base[tid] = (ps[tid] - bt) + ((tid < B) ? chunkoff[c * B + tid] : 0);
    cnt[tid] = 0;
    __syncthreads();
    #pragma unroll 4
    for (int k = 0; k < CHK / 256; ++k) {
        int e = c * CHK + k * 256 + tid;
        if (e < E) {
            int d = edst[e];
            int b = d >> 8;
            int r = atomicAdd(&cnt[b], 1);
            edata[base[b] + r] =
                ((uint)esrc[e] << 12) | ((uint)(d & 255) << 4) | (uint)etyp[e];
        }
    }
}
__global__ void k_p2(const uint* __restrict__ edata, const int* __restrict__ bucktot,
                     uint* __restrict__ epack, int* __restrict__ offs,
                     int N, int E, int B) {
    __shared__ int ps[256];
    __shared__ uint ed[P2CAP];
    __shared__ int cnt[256], off[256], cur[256];
    int b = blockIdx.x, tid = threadIdx.x;
    int bt = (tid < B) ? bucktot[tid] : 0;
    ps[tid] = bt;
    __syncthreads();
    for (int o = 1; o < 256; o <<= 1) {
        int v = (tid >= o) ? ps[tid - o] : 0;
        __syncthreads();
        ps[tid] += v;
        __syncthreads();
    }
    int j0 = ps[b] - ((b < B) ? bucktot[b] : 0);   // exclusive prefix of bucket b
    int count = ps[b] - j0;
    if (count > P2CAP) count = P2CAP;
    for (int i = tid; i < count; i += 256) ed[i] = edata[j0 + i];
    cnt[tid] = 0;
    __syncthreads();
    for (int i = tid; i < count; i += 256) atomicAdd(&cnt[(ed[i] >> 4) & 255], 1);
    __syncthreads();
    int myc = cnt[tid];
    ps[tid] = myc;
    __syncthreads();
    for (int o = 1; o < 256; o <<= 1) {
        int v = (tid >= o) ? ps[tid - o] : 0;
        __syncthreads();
        ps[tid] += v;
        __syncthreads();
    }
    off[tid] = ps[tid] - myc;
    cur[tid] = ps[tid] - myc;
    __syncthreads();
    for (int i = tid; i < count; i += 256) {
        uint v = ed[i];
        int dl = (v >> 4) & 255;
        int r = atomicAdd(&cur[dl], 1);
        epack[j0 + r] = ((v & 15u) << 28) | (v >> 12);
    }
    int v = b * 256 + tid;
    if (v < N) offs[v] = j0 + off[tid];
    if (b == 0 && tid == 0) offs[N] = E;
}

// ---------- shared GEMM building blocks (proven in k_gm since R7) -------------
__device__ __forceinline__ void gl_lds16(const void* g, void* l) {
    __builtin_amdgcn_global_load_lds((const AS1 void*)g, (AS3 void*)l, 16, 0, 0);
}
__device__ __forceinline__ void stage_half(const ushort* __restrict__ Wt, int q,
                                           ushort* bsm0, int wave, int lane) {
    const char* g = (const char*)Wt + (size_t)q * 16384 + lane * 16;
    char* l = (char*)bsm0 + (q & 1) * 16384;
    #pragma unroll
    for (int i = 0; i < 4; ++i) {
        int c = i * 4 + wave;
        gl_lds16(g + c * 1024, l + c * 1024);
    }
}
__device__ __forceinline__ void stage_mlp_slice(const ushort* __restrict__ Wt, int nt,
                                                ushort* bsm0, int wave, int lane) {
    const char* g = (const char*)Wt + (size_t)(9 + wave) * 32768 + nt * 4096 + lane * 16;
    char* l = (char*)bsm0 + (nt & 1) * 16384 + wave * 4096;
    #pragma unroll
    for (int i = 0; i < 4; ++i)
        gl_lds16(g + i * 1024, l + i * 1024);
}
__device__ __forceinline__ void aloadG(short8 (&d)[4], const ushort* p, int off, int ao) {
    #pragma unroll
    for (int ks = 0; ks < 4; ++ks)
        d[ks] = *(const short8*)(p + off + ks * 32 + ao);
}
__device__ __forceinline__ void convHalf(float4v (&acc)[8], const short8 (&a)[4],
                                         const ushort* bsm_h, int h, int lane) {
    #pragma unroll
    for (int nt4 = 0; nt4 < 4; ++nt4) {
        #pragma unroll
        for (int ks = 0; ks < 4; ++ks) {
            short8 b = *(const short8*)(bsm_h + (((nt4 * 4 + ks) * 64 + lane) << 3));
            acc[h * 4 + nt4] = __builtin_amdgcn_mfma_f32_16x16x32_bf16(
                a[ks], b, acc[h * 4 + nt4], 0, 0, 0);
        }
    }
}

// ---------- K_H (R15): h[r] = y @ W_rel[r], r=0..7 ----------------------------
// Transform-then-gather reorder (matches the reference's own factorization):
// dense GEMM per relation, A (16 y rows/wave) loaded ONCE, W staged in the
// proven 16KB half ping-pong (Wt mats 1..8 = halves 2..17). Output h slab r
// row-major bf16 [8][N][128].
__launch_bounds__(256, 4)
__global__ void k_h(const ushort* __restrict__ ybuf, const ushort* __restrict__ Wt,
                    ushort* __restrict__ h, int N) {
    __shared__ ushort bsm[2][8192];
    ushort* bsm0 = &bsm[0][0];
    int tid = threadIdx.x;
    int wave = tid >> 6, lane = tid & 63;
    int quad = lane >> 4, l15 = lane & 15;
    int ao = quad * 8;
    int base = blockIdx.x * 64 + wave * 16;
    const ushort* yrow = ybuf + (size_t)min(base + l15, N - 1) * 128;

    short8 aY[4];
    aloadG(aY, yrow, 0, ao);
    stage_half(Wt, 2, bsm0, wave, lane);                // mat1 half0 -> bsm[0]
    __syncthreads();

    #pragma unroll
    for (int r = 0; r < 8; ++r) {
        float4v acc[8];
        #pragma unroll
        for (int nt = 0; nt < 8; ++nt) acc[nt] = (float4v){0.f, 0.f, 0.f, 0.f};
        stage_half(Wt, 3 + 2 * r, bsm0, wave, lane);    // half1 -> bsm[1]
        convHalf(acc, aY, bsm0, 0, lane);
        __syncthreads();
        if (r < 7) stage_half(Wt, 4 + 2 * r, bsm0, wave, lane);  // next half0 -> bsm[0]
        convHalf(acc, aY, bsm0 + 8192, 1, lane);
        #pragma unroll
        for (int nt = 0; nt < 8; ++nt) {
            int col = nt * 16 + l15;
            #pragma unroll
            for (int rr = 0; rr < 4; ++rr) {
                int row = base + quad * 4 + rr;
                if (row < N)
                    h[((size_t)r * N + row) * 128 + col] = f2bf(acc[nt][rr]);
            }
        }
        __syncthreads();
    }
}

// ---------- K3 (R15): agg[v] = sum over edges of h[type][src] -----------------
// R7's proven gather structure verbatim (coalesced 64-edge chunk + shfl
// broadcast + 4-deep independent row loads, 50000-wave TLP); relation now
// selects the h SLAB in the address, and the 8 accumulators collapse to 4
// ILP pairs summed at the end. Output agg = N x 128 bf16 (12.8MB, 8x less
// write than zbuf).
__global__ void k_zagg(const ushort* __restrict__ h, const int* __restrict__ offs,
                       const uint* __restrict__ epack, ushort* __restrict__ agg, int N) {
    int wave = threadIdx.x >> 6;
    int l = threadIdx.x & 63;
    int v = blockIdx.x * 4 + wave;
    if (v >= N) return;
    float2 a0 = {0.f,0.f}, a1 = {0.f,0.f}, a2 = {0.f,0.f}, a3 = {0.f,0.f};
    const uint* hb = (const uint*)h;
    size_t Ns = (size_t)N;
    int j = offs[v], e1 = offs[v + 1];
    while (j < e1) {
        int chunk = min(64, e1 - j);
        uint pl = (j + l < e1) ? epack[j + l] : 0;
        int i = 0;
        for (; i + 3 < chunk; i += 4) {
            uint p0 = __shfl(pl, i, 64);
            uint p1 = __shfl(pl, i + 1, 64);
            uint p2 = __shfl(pl, i + 2, 64);
            uint p3 = __shfl(pl, i + 3, 64);
            uint u0 = hb[((size_t)(p0 >> 28) * Ns + (p0 & 0x0FFFFFFFu)) * 64 + l];
            uint u1 = hb[((size_t)(p1 >> 28) * Ns + (p1 & 0x0FFFFFFFu)) * 64 + l];
            uint u2 = hb[((size_t)(p2 >> 28) * Ns + (p2 & 0x0FFFFFFFu)) * 64 + l];
            uint u3 = hb[((size_t)(p3 >> 28) * Ns + (p3 & 0x0FFFFFFFu)) * 64 + l];
            a0.x += bf_lo(u0); a0.y += bf_hi(u0);
            a1.x += bf_lo(u1); a1.y += bf_hi(u1);
            a2.x += bf_lo(u2); a2.y += bf_hi(u2);
            a3.x += bf_lo(u3); a3.y += bf_hi(u3);
        }
        for (; i < chunk; ++i) {
            uint p = __shfl(pl, i, 64);
            uint u = hb[((size_t)(p >> 28) * Ns + (p & 0x0FFFFFFFu)) * 64 + l];
            a0.x += bf_lo(u); a0.y += bf_hi(u);
        }
        j += chunk;
    }
    float lo = (a0.x + a1.x) + (a2.x + a3.x);
    float hi = (a0.y + a1.y) + (a2.y + a3.y);
    ((uint*)agg)[(size_t)v * 64 + l] = ((uint)f2bf(hi) << 16) | f2bf(lo);
}

// ---------- K4 (R15): conv K=128 (W_root only) + agg + LN2 + ReLU + MLP -------
// 26 phases -> 10: the 8 per-relation conv mats moved to k_h; agg is added in
// the epilogue (bf16 scalar reads, 12.8MB). Everything else is the proven R7
// structure (32KB LDS, y2-overlay on bsm[1], per-nt MLP slices).
__launch_bounds__(256, 4)
__global__ void k_gm(const ushort* __restrict__ ybuf, const ushort* __restrict__ agg,
                     const ushort* __restrict__ Wt, const float* __restrict__ x,
                     const int* __restrict__ ntp,
                     const float* __restrict__ gamma, const float* __restrict__ beta,
                     const float* __restrict__ bmlp, float* __restrict__ out, int N) {
    __shared__ ushort bsm[2][8192];      // ping-pong; bsm[1] doubles as y2 overlay
    ushort* bsm0 = &bsm[0][0];
    int tid = threadIdx.x;
    int wave = tid >> 6, lane = tid & 63;
    int quad = lane >> 4, l15 = lane & 15;
    int ao = quad * 8;
    int base = blockIdx.x * 64 + wave * 16;             // 16 rows per wave

    const ushort* yrow = ybuf + (size_t)min(base + l15, N - 1) * 128;

    float4v acc[8];
    #pragma unroll
    for (int nt = 0; nt < 8; ++nt) acc[nt] = (float4v){0.f, 0.f, 0.f, 0.f};

    short8 aC[4];
    stage_half(Wt, 0, bsm0, wave, lane);                // W_root half0 -> bsm[0]
    aloadG(aC, yrow, 0, ao);
    __syncthreads();

    stage_half(Wt, 1, bsm0, wave, lane);                // W_root half1 -> bsm[1]
    convHalf(acc, aC, bsm0, 0, lane);
    __syncthreads();
    stage_mlp_slice(Wt, 0, bsm0, wave, lane);           // MLP slice 0 -> bsm[0]
    convHalf(acc, aC, bsm0 + 8192, 1, lane);
    __syncthreads();

    // epilogue: x2 = x + agg + y@W_root (kept in acc); LN2 + ReLU -> y2 overlay
    ushort* yov = bsm0 + 8192 + wave * 2048;
    int ty[4];
    {
        float s[4] = {0.f, 0.f, 0.f, 0.f}, s2[4] = {0.f, 0.f, 0.f, 0.f};
        #pragma unroll
        for (int nt = 0; nt < 8; ++nt) {
            int col = nt * 16 + l15;
            #pragma unroll
            for (int r = 0; r < 4; ++r) {
                int row = base + quad * 4 + r;
                float xv = 0.f, av = 0.f;
                if (row < N) {
                    xv = x[(size_t)row * D + col];
                    av = __uint_as_float((uint)agg[(size_t)row * 128 + col] << 16);
                }
                float t = acc[nt][r] + xv + av;
                acc[nt][r] = t;
                s[r] += t; s2[r] += t * t;
            }
        }
        #pragma unroll
        for (int r = 0; r < 4; ++r) {
            #pragma unroll
            for (int o = 1; o < 16; o <<= 1) {
                s[r]  += __shfl_xor(s[r],  o, 64);
                s2[r] += __shfl_xor(s2[r], o, 64);
            }
        }
        #pragma unroll
        for (int r = 0; r < 4; ++r) {
            int rc = min(base + quad * 4 + r, N - 1);
            ty[r] = ntp[rc];
            float mu  = s[r] * (1.0f / D);
            float var = s2[r] * (1.0f / D) - mu * mu;
            float inv = rsqrtf(var + EPS);
            int lrow = quad * 4 + r;
            #pragma unroll
            for (int nt = 0; nt < 8; ++nt) {
                int col = nt * 16 + l15;
                float yn = fmaxf((acc[nt][r] - mu) * inv * gamma[ty[r] * D + col]
                                 + beta[ty[r] * D + col], 0.f);
                yov[lrow * 128 + col] = f2bf(yn);
            }
        }
    }
    short8 a2[4];
    {
        const ushort* myrow = yov + l15 * 128;
        #pragma unroll
        for (int ks = 0; ks < 4; ++ks) a2[ks] = *(const short8*)(myrow + ks * 32 + ao);
    }
    __syncthreads();    // a2 settled before slice-1 staging clobbers overlay

    #pragma unroll
    for (int nt = 0; nt < 8; ++nt) {
        if (nt < 7) stage_mlp_slice(Wt, nt + 1, bsm0, wave, lane);
        const ushort* bh = bsm0 + (nt & 1) * 8192;
        float4v c0 = {0.f,0.f,0.f,0.f}, c1 = {0.f,0.f,0.f,0.f};
        float4v c2 = {0.f,0.f,0.f,0.f}, c3 = {0.f,0.f,0.f,0.f};
        #pragma unroll
        for (int ks = 0; ks < 4; ++ks) {
            int fo = (ks * 64 + lane) << 3;
            short8 b0 = *(const short8*)(bh + 0 * 2048 + fo);
            short8 b1 = *(const short8*)(bh + 1 * 2048 + fo);
            short8 b2 = *(const short8*)(bh + 2 * 2048 + fo);
            short8 b3 = *(const short8*)(bh + 3 * 2048 + fo);
            c0 = __builtin_amdgcn_mfma_f32_16x16x32_bf16(a2[ks], b0, c0, 0, 0, 0);
            c1 = __builtin_amdgcn_mfma_f32_16x16x32_bf16(a2[ks], b1, c1, 0, 0, 0);
            c2 = __builtin_amdgcn_mfma_f32_16x16x32_bf16(a2[ks], b2, c2, 0, 0, 0);
            c3 = __builtin_amdgcn_mfma_f32_16x16x32_bf16(a2[ks], b3, c3, 0, 0, 0);
        }
        int col = nt * 16 + l15;
        #pragma unroll
        for (int r = 0; r < 4; ++r) {
            int row = base + quad * 4 + r;
            if (row < N) {
                int t = ty[r];
                float v = (t == 0) ? c0[r] : (t == 1) ? c1[r] : (t == 2) ? c2[r] : c3[r];
                out[(size_t)row * D + col] = acc[nt][r] + v + bmlp[t * D + col];
            }
        }
        if (nt < 7) __syncthreads();
    }
}

// ---------- launch ------------------------------------------------------------
extern "C" void kernel_launch(void* const* d_in, const int* in_sizes, int n_in,
                              void* d_out, int out_size, void* d_ws, size_t ws_size,
                              hipStream_t stream) {
    const float* x          = (const float*)d_in[0];
    const int*   esrc       = (const int*)d_in[1];
    const int*   edst       = (const int*)d_in[2];
    const int*   ntyp       = (const int*)d_in[3];
    const int*   etyp       = (const int*)d_in[4];
    const float* conv_gamma = (const float*)d_in[5];
    const float* conv_beta  = (const float*)d_in[6];
    const float* W_rel      = (const float*)d_in[7];
    const float* W_root     = (const float*)d_in[8];
    const float* mlp_gamma  = (const float*)d_in[9];
    const float* mlp_beta   = (const float*)d_in[10];
    const float* W_mlp      = (const float*)d_in[11];
    const float* b_mlp      = (const float*)d_in[12];
    float* out = (float*)d_out;

    int N = in_sizes[0] / D;
    int E = in_sizes[1];
    int C = (E + CHK - 1) / CHK;        // chunks (<=128)
    int B = (N + 255) / 256;            // coarse buckets (<=256)

    char* p = (char*)d_ws;
    auto take = [&p](size_t bytes) { char* q = p; p += (bytes + 255) & ~(size_t)255; return q; };
    ushort* ybuf    = (ushort*)take((size_t)N * D * 2);
    ushort* h       = (ushort*)take((size_t)8 * N * D * 2);   // [8][N][128] bf16
    ushort* agg     = (ushort*)take((size_t)N * D * 2);
    ushort* Wt      = (ushort*)take((size_t)13 * D * D * 2);
    uint*   edata   = (uint*)take((size_t)E * 4);
    uint*   epack   = (uint*)take((size_t)E * 4);
    int*    offs    = (int*)take((size_t)(N + 1) * 4);
    int*    hist    = (int*)take((size_t)C * B * 4);
    int*    chunkoff= (int*)take((size_t)C * B * 4);
    int*    bucktot = (int*)take((size_t)B * 4);

    // K1: weights + LN1 + fused chunk-hist
    k_ln1cvt<<<13 + (N + 3) / 4, 256, 0, stream>>>(x, ntyp, conv_gamma, conv_beta,
                                                   ybuf, W_rel, W_root, W_mlp, Wt,
                                                   edst, hist, N, E, C, B);

    // per-relation transform (independent of the sort chain)
    k_h<<<(N + 63) / 64, 256, 0, stream>>>(ybuf, Wt, h, N);

    k_c2<<<B, 128, 0, stream>>>(hist, chunkoff, bucktot, C, B);
    k_p1s<<<C, 256, 0, stream>>>(edst, esrc, etyp, bucktot, chunkoff, edata, E, B);
    k_p2<<<B, 256, 0, stream>>>(edata, bucktot, epack, offs, N, E, B);

    k_zagg<<<(N + 3) / 4, 256, 0, stream>>>(h, offs, epack, agg, N);

    k_gm<<<(N + 63) / 64, 256, 0, stream>>>(ybuf, agg, Wt, x, ntyp,
                                            mlp_gamma, mlp_beta, b_mlp, out, N);
}